// Round 1
// baseline (89.146 us; speedup 1.0000x reference)
//
#include <hip/hip_runtime.h>

#define NHID 25
#define NSTEP 20
#define DT_ (1.0f/60.0f)
#define EPS_ 1e-4f
#define PQ_ 5.0f
#define QV_ 200.0f
#define QA_ 1.0f
#define NAUG (NSTEP + 2)      // 22 columns: [Qf | phi | rho]
#define NEL  (NSTEP * NAUG)   // 440 elements

// ---------------------------------------------------------------------------
// R6 restructure: the entire setup (phases A/B, 20-pivot Gauss-Jordan, phase
// C) depends ONLY on Af,Lq and produces exactly 65 floats (us[25], bs[20],
// gs[20]). Previously every one of 512 blocks recomputed it -- a serial
// latency chain (~450-600 cy/pivot * 20 pivots + 5 extra barriers) that left
// the kernel >20x above the 3.9 us memory roofline (24.6 MB @ 6.3 TB/s).
// Now: kernel 1 (one block) computes the 65 constants into d_ws; kernel 2 is
// a pure streaming epilogue at full occupancy. Same-stream ordering + the
// implicit end-of-kernel release makes the ws write visible to kernel 2
// (no cross-XCD coherence hazard). Math path is identical -> same absmax.
// ---------------------------------------------------------------------------

// ============================ kernel 1: setup ==============================
__global__ __launch_bounds__(256) void mpc_setup(
    const float* __restrict__ Af, const float* __restrict__ Lq,
    float* __restrict__ cst)   // cst[0:25]=us, [25:45]=bs, [45:65]=gs
{
    __shared__ float Lqs[NHID * NHID];
    __shared__ float Afs[NHID];
    __shared__ float wv_[NHID];
    __shared__ float us[NHID];
    __shared__ float alpha_s;
    __shared__ float aug[NSTEP][NAUG + 2]; // pad stride to 24 floats

    const int t = threadIdx.x;
    const float dt = DT_;

    if (t < NHID) Afs[t] = Af[t];
    for (int i = t; i < NHID * NHID; i += 256) Lqs[i] = Lq[i];
    __syncthreads();

    // ---- phase A: w = Lq^T Af ; u = Lq w + eps Af ; alpha = Af . u ----
    if (t < NHID) {
        float acc = 0.0f;
        for (int i = t; i < NHID; ++i)
            acc = fmaf(Lqs[i * NHID + t], Afs[i], acc);
        wv_[t] = acc;
    }
    __syncthreads();
    if (t < NHID) {
        float acc = EPS_ * Afs[t];
        for (int j = 0; j <= t; ++j)
            acc = fmaf(Lqs[t * NHID + j], wv_[j], acc);
        us[t] = acc;
    }
    __syncthreads();
    if (t == 0) {
        float a = 0.0f;
        for (int i = 0; i < NHID; ++i) a = fmaf(Afs[i], us[i], a);
        alpha_s = a;
    }
    __syncthreads();
    const float alpha = alpha_s;

    // ---- phase B: build [Qf | phi | rho], 440 elems striped over 256 thr ----
    for (int idx = t; idx < NEL; idx += 256) {
        int r = idx / NAUG, c = idx % NAUG;
        float val;
        if (c < NSTEP) {
            int m0 = (r > c) ? r : c;
            float s = 0.0f;
            for (int rr = m0; rr < NSTEP; ++rr) {
                float wr = (rr == NSTEP - 1) ? PQ_ : 1.0f;
                s = fmaf(wr, fmaf((float)(rr - r) * (float)(rr - c), alpha, QV_), s);
            }
            val = 2.0f * dt * dt * s + ((r == c) ? (2.0f * QA_ + EPS_) : 0.0f);
        } else if (c == NSTEP) {
            float s = 0.0f;
            for (int rr = r; rr < NSTEP; ++rr)
                s += ((rr == NSTEP - 1) ? PQ_ : 1.0f) * (float)(rr - r);
            val = s;
        } else {
            float s = 0.0f;
            for (int rr = r; rr < NSTEP; ++rr) {
                float wr = (rr == NSTEP - 1) ? PQ_ : 1.0f;
                s = fmaf(wr, fmaf((float)(rr + 1) * (float)(rr - r), alpha, QV_), s);
            }
            val = s;
        }
        aug[r][c] = val;
    }
    __syncthreads();

    // ---- Gauss-Jordan in LDS: 2 barriers/pivot, broadcast reads free ----
    const int r0 = t / NAUG,         c0 = t % NAUG;          // elem 0 (t<440)
    const int r1 = (t + 256) / NAUG, c1 = (t + 256) % NAUG;  // elem 1 (t<184)
    for (int piv = 0; piv < NSTEP; ++piv) {
        float app  = aug[piv][piv];                  // broadcast
        float pinv = 1.0f / app;
        float n0 = 0.0f, n1 = 0.0f;
        if (t < NEL) {
            float arc = aug[r0][c0], apc = aug[piv][c0], arp = aug[r0][piv];
            n0 = (r0 == piv) ? arc * pinv : fmaf(-arp * pinv, apc, arc);
        }
        if (t < NEL - 256) {
            float arc = aug[r1][c1], apc = aug[piv][c1], arp = aug[r1][piv];
            n1 = (r1 == piv) ? arc * pinv : fmaf(-arp * pinv, apc, arc);
        }
        __syncthreads();
        if (t < NEL)       aug[r0][c0] = n0;
        if (t < NEL - 256) aug[r1][c1] = n1;
        __syncthreads();
    }

    // ---- phase C: bvec, gvec from z1=aug[.][20], z2=aug[.][21] ----
    if (t < NSTEP) {
        const float hdt2 = 0.5f * dt * dt;
        float bacc = 0.0f, gacc = 0.0f;
        for (int c = 0; c <= t; ++c) {
            float ssel = fmaf((float)(t - c), dt * dt, hdt2);
            bacc = fmaf(aug[c][NSTEP],     ssel, bacc);
            gacc = fmaf(aug[c][NSTEP + 1], ssel, gacc);
        }
        cst[NHID + t]         = -2.0f * dt * bacc;
        cst[NHID + NSTEP + t] = fmaf((float)(t + 1), dt, -2.0f * dt * gacc);
    }
    if (t < NHID) cst[t] = us[t];
}

// ============================ kernel 2: stream =============================
__global__ __launch_bounds__(256) void mpc_stream(
    const float* __restrict__ x, const float* __restrict__ gp,
    const float* __restrict__ gv, const float* __restrict__ cst,
    float* __restrict__ out)
{
    __shared__ float xs[256 * NHID];       // 25600 B -> 6 blocks/CU by LDS
    __shared__ float us[NHID];
    __shared__ float bs[NSTEP];
    __shared__ float gs[NSTEP];

    const int t = threadIdx.x;
    const size_t b0 = (size_t)blockIdx.x * 256;

    // ---- stage constants (65 floats, L2-hot broadcast) ----
    if (t < NHID + 2 * NSTEP) {
        float c = cst[t];
        if (t < NHID)              us[t] = c;
        else if (t < NHID + NSTEP) bs[t - NHID] = c;
        else                       gs[t - NHID - NSTEP] = c;
    }

    // ---- stage x tile, coalesced float4 (6400 floats = 1600 float4) ----
    {
        const float4* xsrc = (const float4*)(x + b0 * NHID);
        float4* xdst = (float4*)xs;
        #pragma unroll
        for (int i = 0; i < 7; ++i) {
            int idx = t + 256 * i;
            if (idx < 1600) xdst[idx] = xsrc[idx];
        }
    }
    const float p = gp[b0 + t];
    const float v = gv[b0 + t];
    __syncthreads();

    // ---- out[b,k] = p + (x_b . us)*bs[k] + v*gs[k] ----
    const float* xr = xs + t * NHID;
    float tb = 0.0f;
    #pragma unroll
    for (int i = 0; i < NHID; ++i)
        tb = fmaf(xr[i], us[i], tb);

    float4* o4 = (float4*)(out + (b0 + t) * NSTEP);
    #pragma unroll
    for (int q = 0; q < 5; ++q) {
        float4 r;
        r.x = fmaf(tb, bs[4*q+0], fmaf(v, gs[4*q+0], p));
        r.y = fmaf(tb, bs[4*q+1], fmaf(v, gs[4*q+1], p));
        r.z = fmaf(tb, bs[4*q+2], fmaf(v, gs[4*q+2], p));
        r.w = fmaf(tb, bs[4*q+3], fmaf(v, gs[4*q+3], p));
        o4[q] = r;
    }
}

extern "C" void kernel_launch(void* const* d_in, const int* in_sizes, int n_in,
                              void* d_out, int out_size, void* d_ws, size_t ws_size,
                              hipStream_t stream) {
    const float* x  = (const float*)d_in[0];
    const float* gp = (const float*)d_in[1];
    const float* gv = (const float*)d_in[2];
    const float* Af = (const float*)d_in[3];
    const float* Lq = (const float*)d_in[4];
    float* out = (float*)d_out;
    float* cst = (float*)d_ws;            // 65 floats; re-written every call

    const int B = in_sizes[1];            // BATCH

    hipLaunchKernelGGL(mpc_setup, dim3(1), dim3(256), 0, stream, Af, Lq, cst);
    hipLaunchKernelGGL(mpc_stream, dim3(B / 256), dim3(256), 0, stream,
                       x, gp, gv, cst, out);
}

// Round 2
// 87.134 us; speedup vs baseline: 1.0231x; 1.0231x over previous
//
#include <hip/hip_runtime.h>

#define NHID 25
#define NSTEP 20
#define DT_ (1.0f/60.0f)
#define EPS_ 1e-4f
#define PQ_ 5.0f
#define QV_ 200.0f
#define QA_ 1.0f
#define NAUG (NSTEP + 2)      // 22 columns: [Qf | phi | rho]
#define NEL  (NSTEP * NAUG)   // 440 elements

// ---------------------------------------------------------------------------
// R7: REVERT to the fused single-launch kernel (best measured: 85.6 us R0,
// 86.7 us prev session). Evidence from R6 post-mortem: dur_us is dominated by
// two harness 256-MiB workspace poison fills (2 x ~42.7 us at ~78% HBM peak,
// present whether or not d_ws is used); our kernel contributes <~4 us. The
// R6 setup/stream split ADDED ~3.5 us: an extra graph node plus a serial
// 1-block setup kernel (~4 us latency chain) that cannot overlap anything.
// The fused form hides per-block setup under other blocks' HBM streaming.
//
// Closed forms (HW-verified R2-R5):
//   u = Q0*Af, alpha = Af^T Q0 Af          (Q0 = Lq Lq^T + eps I)
//   Qf[r][c] = (2QA+EPS)delta + 2dt^2 sum_{rr>=max} w_rr((rr-r)(rr-c)alpha+QV)
//   phi[r] = sum_{rr>=r} w_rr (rr-r)
//   rho[r] = sum_{rr>=r} w_rr ((rr+1)(rr-r)alpha + QV)
//   [z1 z2] = Qf^{-1} [phi rho]
//   bvec[k] = -2dt sum_{c<=k} z1[c](hdt2+(k-c)dt^2)
//   gvec[k] = (k+1)dt - 2dt sum_{c<=k} z2[c](hdt2+(k-c)dt^2)
//   out[b,k] = gp_b + (x_b . u)*bvec[k] + gv_b*gvec[k]
//
// GJ strategy (R3/R4/R5 lesson): register+shuffle GJ ALWAYS serializes
// (~110cyc/ds_bpermute, compiler won't batch; 20x22 shfls ~ 20us). Here the
// 20x22 system lives in LDS and all 256 threads update it with 2 barriers
// per pivot; pivot row/col reads are same-address broadcasts (free). ~2.5us.
// Every block recomputes setup redundantly: no 2nd launch, no cross-block
// handoff, overlaps with other blocks' HBM streaming.
// ---------------------------------------------------------------------------
__global__ __launch_bounds__(256) void mpc_fused(
    const float* __restrict__ x, const float* __restrict__ gp,
    const float* __restrict__ gv, const float* __restrict__ Af,
    const float* __restrict__ Lq, float* __restrict__ out)
{
    __shared__ float xs[256 * NHID];       // 25600 B
    __shared__ float Lqs[NHID * NHID];     // 2500 B
    __shared__ float Afs[NHID];
    __shared__ float wv_[NHID];
    __shared__ float us[NHID];
    __shared__ float alpha_s;
    __shared__ float aug[NSTEP][NAUG + 2]; // pad stride to 24 floats
    __shared__ float bs[NSTEP];
    __shared__ float gs[NSTEP];

    const int t = threadIdx.x;
    const size_t b0 = (size_t)blockIdx.x * 256;
    const float dt = DT_;

    // ---- stage everything (all global loads issue up-front) ----
    if (t < NHID) Afs[t] = Af[t];
    for (int i = t; i < NHID * NHID; i += 256) Lqs[i] = Lq[i];
    {
        const float4* xsrc = (const float4*)(x + b0 * NHID);
        float4* xdst = (float4*)xs;
        #pragma unroll
        for (int i = 0; i < 7; ++i) {
            int idx = t + 256 * i;
            if (idx < 1600) xdst[idx] = xsrc[idx];     // 6400 floats
        }
    }
    const float p = gp[b0 + t];
    const float v = gv[b0 + t];
    __syncthreads();

    // ---- phase A: w = Lq^T Af ; u = Lq w + eps Af ; alpha = Af . u ----
    if (t < NHID) {
        float acc = 0.0f;
        for (int i = t; i < NHID; ++i)
            acc = fmaf(Lqs[i * NHID + t], Afs[i], acc);
        wv_[t] = acc;
    }
    __syncthreads();
    if (t < NHID) {
        float acc = EPS_ * Afs[t];
        for (int j = 0; j <= t; ++j)
            acc = fmaf(Lqs[t * NHID + j], wv_[j], acc);
        us[t] = acc;
    }
    __syncthreads();
    if (t == 0) {
        float a = 0.0f;
        for (int i = 0; i < NHID; ++i) a = fmaf(Afs[i], us[i], a);
        alpha_s = a;
    }
    __syncthreads();
    const float alpha = alpha_s;

    // ---- phase B: build [Qf | phi | rho], 440 elems striped over 256 thr ----
    for (int idx = t; idx < NEL; idx += 256) {
        int r = idx / NAUG, c = idx % NAUG;
        float val;
        if (c < NSTEP) {
            int m0 = (r > c) ? r : c;
            float s = 0.0f;
            for (int rr = m0; rr < NSTEP; ++rr) {
                float wr = (rr == NSTEP - 1) ? PQ_ : 1.0f;
                s = fmaf(wr, fmaf((float)(rr - r) * (float)(rr - c), alpha, QV_), s);
            }
            val = 2.0f * dt * dt * s + ((r == c) ? (2.0f * QA_ + EPS_) : 0.0f);
        } else if (c == NSTEP) {
            float s = 0.0f;
            for (int rr = r; rr < NSTEP; ++rr)
                s += ((rr == NSTEP - 1) ? PQ_ : 1.0f) * (float)(rr - r);
            val = s;
        } else {
            float s = 0.0f;
            for (int rr = r; rr < NSTEP; ++rr) {
                float wr = (rr == NSTEP - 1) ? PQ_ : 1.0f;
                s = fmaf(wr, fmaf((float)(rr + 1) * (float)(rr - r), alpha, QV_), s);
            }
            val = s;
        }
        aug[r][c] = val;
    }
    __syncthreads();

    // ---- Gauss-Jordan in LDS: 2 barriers/pivot, broadcast reads are free ----
    const int r0 = t / NAUG,        c0 = t % NAUG;          // elem 0 (t<440)
    const int r1 = (t + 256) / NAUG, c1 = (t + 256) % NAUG; // elem 1 (t<184)
    for (int piv = 0; piv < NSTEP; ++piv) {
        float app  = aug[piv][piv];                  // broadcast
        float pinv = 1.0f / app;
        float n0 = 0.0f, n1 = 0.0f;
        if (t < NEL) {
            float arc = aug[r0][c0], apc = aug[piv][c0], arp = aug[r0][piv];
            n0 = (r0 == piv) ? arc * pinv : fmaf(-arp * pinv, apc, arc);
        }
        if (t < NEL - 256) {
            float arc = aug[r1][c1], apc = aug[piv][c1], arp = aug[r1][piv];
            n1 = (r1 == piv) ? arc * pinv : fmaf(-arp * pinv, apc, arc);
        }
        __syncthreads();
        if (t < NEL)       aug[r0][c0] = n0;
        if (t < NEL - 256) aug[r1][c1] = n1;
        __syncthreads();
    }

    // ---- phase C: bvec, gvec from z1=aug[.][20], z2=aug[.][21] ----
    if (t < NSTEP) {
        const float hdt2 = 0.5f * dt * dt;
        float bacc = 0.0f, gacc = 0.0f;
        for (int c = 0; c <= t; ++c) {
            float ssel = fmaf((float)(t - c), dt * dt, hdt2);
            bacc = fmaf(aug[c][NSTEP],     ssel, bacc);
            gacc = fmaf(aug[c][NSTEP + 1], ssel, gacc);
        }
        bs[t] = -2.0f * dt * bacc;
        gs[t] = fmaf((float)(t + 1), dt, -2.0f * dt * gacc);
    }
    __syncthreads();

    // ---- batch epilogue: out[b,k] = p + tb*bs[k] + v*gs[k] ----
    const float* xr = xs + t * NHID;
    float tb = 0.0f;
    #pragma unroll
    for (int i = 0; i < NHID; ++i)
        tb = fmaf(xr[i], us[i], tb);

    float4* o4 = (float4*)(out + (b0 + t) * NSTEP);
    #pragma unroll
    for (int q = 0; q < 5; ++q) {
        float4 r;
        r.x = fmaf(tb, bs[4*q+0], fmaf(v, gs[4*q+0], p));
        r.y = fmaf(tb, bs[4*q+1], fmaf(v, gs[4*q+1], p));
        r.z = fmaf(tb, bs[4*q+2], fmaf(v, gs[4*q+2], p));
        r.w = fmaf(tb, bs[4*q+3], fmaf(v, gs[4*q+3], p));
        o4[q] = r;
    }
}

extern "C" void kernel_launch(void* const* d_in, const int* in_sizes, int n_in,
                              void* d_out, int out_size, void* d_ws, size_t ws_size,
                              hipStream_t stream) {
    const float* x  = (const float*)d_in[0];
    const float* gp = (const float*)d_in[1];
    const float* gv = (const float*)d_in[2];
    const float* Af = (const float*)d_in[3];
    const float* Lq = (const float*)d_in[4];
    float* out = (float*)d_out;

    const int B = in_sizes[1];            // BATCH
    hipLaunchKernelGGL(mpc_fused, dim3(B / 256), dim3(256), 0, stream,
                       x, gp, gv, Af, Lq, out);
}